// Round 1
// baseline (969.311 us; speedup 1.0000x reference)
//
#include <hip/hip_runtime.h>

namespace {

constexpr int NJ = 24;

struct Xf { float r[9]; float t[3]; };

__device__ __forceinline__ void rodrigues(float x, float y, float z, float R[9]) {
    float n2 = x*x + y*y + z*z + 1e-8f;
    float th = sqrtf(n2);
    float inv = 1.0f / th;
    float ax = x * inv, ay = y * inv, az = z * inv;
    float s = __sinf(th);
    float c = __cosf(th);
    float C = 1.0f - c;
    float aa = ax*ax + ay*ay + az*az;
    float xy = C*ax*ay, xz = C*ax*az, yz = C*ay*az;
    float sx = s*ax, sy = s*ay, sz = s*az;
    R[0] = 1.0f + C*(ax*ax - aa);
    R[1] = xy - sz;
    R[2] = xz + sy;
    R[3] = xy + sz;
    R[4] = 1.0f + C*(ay*ay - aa);
    R[5] = yz - sx;
    R[6] = xz - sy;
    R[7] = yz + sx;
    R[8] = 1.0f + C*(az*az - aa);
}

// Emit all per-joint outputs. R,t are the composed (chain) transform with the
// pelvis offset already added to (tx,ty,tz); Rl is the local rotation.
template<int J>
__device__ __forceinline__ void emit_joint(float* __restrict__ out, size_t B, int b,
                                           const float R[9], float tx, float ty, float tz,
                                           const float Rl[9]) {
    // kp: [B,24,3] at offset 0
    float* kp = out + (size_t)b*72 + J*3;
    kp[0] = tx; kp[1] = ty; kp[2] = tz;
    // rots: [B,24,3,3] at offset B*912
    float* rp = out + B*912 + (size_t)b*216 + J*9;
    #pragma unroll
    for (int i = 0; i < 9; ++i) rp[i] = Rl[i];
    // l2ws: [B,24,4,4] at offset B*528 — each matrix is one 64B line, 4x float4
    float4* lp = reinterpret_cast<float4*>(out + B*528 + (size_t)b*384 + J*16);
    lp[0] = make_float4(R[0], R[1], R[2], tx);
    lp[1] = make_float4(R[3], R[4], R[5], ty);
    lp[2] = make_float4(R[6], R[7], R[8], tz);
    lp[3] = make_float4(0.f, 0.f, 0.f, 1.f);
    // skts = inv(l2ws) = [R^T | -R^T t]: [B,24,4,4] at offset B*144
    float4* sp = reinterpret_cast<float4*>(out + B*144 + (size_t)b*384 + J*16);
    sp[0] = make_float4(R[0], R[3], R[6], -(R[0]*tx + R[3]*ty + R[6]*tz));
    sp[1] = make_float4(R[1], R[4], R[7], -(R[1]*tx + R[4]*ty + R[7]*tz));
    sp[2] = make_float4(R[2], R[5], R[8], -(R[2]*tx + R[5]*ty + R[8]*tz));
    sp[3] = make_float4(0.f, 0.f, 0.f, 1.f);
}

template<int J>
__device__ __forceinline__ Xf step(const Xf& P, const float* __restrict__ bn,
                                   const float (*sdt)[3],
                                   float* __restrict__ out, size_t B, int b,
                                   float px, float py, float pz) {
    float Rl[9];
    rodrigues(bn[J*3+0], bn[J*3+1], bn[J*3+2], Rl);
    float d0 = sdt[J][0], d1 = sdt[J][1], d2 = sdt[J][2];
    Xf C;
    C.r[0] = P.r[0]*Rl[0] + P.r[1]*Rl[3] + P.r[2]*Rl[6];
    C.r[1] = P.r[0]*Rl[1] + P.r[1]*Rl[4] + P.r[2]*Rl[7];
    C.r[2] = P.r[0]*Rl[2] + P.r[1]*Rl[5] + P.r[2]*Rl[8];
    C.r[3] = P.r[3]*Rl[0] + P.r[4]*Rl[3] + P.r[5]*Rl[6];
    C.r[4] = P.r[3]*Rl[1] + P.r[4]*Rl[4] + P.r[5]*Rl[7];
    C.r[5] = P.r[3]*Rl[2] + P.r[4]*Rl[5] + P.r[5]*Rl[8];
    C.r[6] = P.r[6]*Rl[0] + P.r[7]*Rl[3] + P.r[8]*Rl[6];
    C.r[7] = P.r[6]*Rl[1] + P.r[7]*Rl[4] + P.r[8]*Rl[7];
    C.r[8] = P.r[6]*Rl[2] + P.r[7]*Rl[5] + P.r[8]*Rl[8];
    C.t[0] = P.r[0]*d0 + P.r[1]*d1 + P.r[2]*d2 + P.t[0];
    C.t[1] = P.r[3]*d0 + P.r[4]*d1 + P.r[5]*d2 + P.t[1];
    C.t[2] = P.r[6]*d0 + P.r[7]*d1 + P.r[8]*d2 + P.t[2];
    emit_joint<J>(out, B, b, C.r, C.t[0]+px, C.t[1]+py, C.t[2]+pz, Rl);
    return C;
}

__device__ const int g_par[NJ] = {0,0,0,0,1,2,3,4,5,6,7,8,9,9,9,12,13,14,16,17,18,19,20,21};

__global__ __launch_bounds__(256)
void pose_kernel(const float* __restrict__ pelvis,
                 const float* __restrict__ bones,
                 const float* __restrict__ rest,
                 const int* __restrict__ idxs,
                 float* __restrict__ out, int Bn)
{
    __shared__ float sdt[NJ][3];
    const int tid = threadIdx.x;
    if (tid < NJ) {
        if (tid == 0) {
            sdt[0][0] = rest[0]; sdt[0][1] = rest[1]; sdt[0][2] = rest[2];
        } else {
            int p = g_par[tid];
            sdt[tid][0] = rest[tid*3+0] - rest[p*3+0];
            sdt[tid][1] = rest[tid*3+1] - rest[p*3+1];
            sdt[tid][2] = rest[tid*3+2] - rest[p*3+2];
        }
    }
    __syncthreads();

    int b = blockIdx.x * 256 + tid;
    if (b >= Bn) return;
    size_t B = (size_t)Bn;

    int idx = idxs[b];
    float px = pelvis[(size_t)idx*3+0];
    float py = pelvis[(size_t)idx*3+1];
    float pz = pelvis[(size_t)idx*3+2];

    // Gather the 24x3 bone vector (288B contiguous) into registers, forwarding
    // straight to the `bone` output (offset B*72) as coalesced-per-thread float4.
    float bn[72];
    const float4* bsrc = reinterpret_cast<const float4*>(bones + (size_t)idx*72);
    float4* bdst = reinterpret_cast<float4*>(out + B*72 + (size_t)b*72);
    #pragma unroll
    for (int k = 0; k < 18; ++k) {
        float4 v = bsrc[k];
        bdst[k] = v;
        bn[4*k+0] = v.x; bn[4*k+1] = v.y; bn[4*k+2] = v.z; bn[4*k+3] = v.w;
    }

    // Root joint
    Xf root;
    {
        float Rl[9];
        rodrigues(bn[0], bn[1], bn[2], Rl);
        #pragma unroll
        for (int i = 0; i < 9; ++i) root.r[i] = Rl[i];
        root.t[0] = sdt[0][0]; root.t[1] = sdt[0][1]; root.t[2] = sdt[0][2];
        emit_joint<0>(out, B, b, root.r, root.t[0]+px, root.t[1]+py, root.t[2]+pz, Rl);
    }

    // Chain branches, fully unrolled. Live state: root, x9, cur only.
    Xf c;
    c = step<1>(root, bn, sdt, out, B, b, px, py, pz);
    c = step<4>(c,    bn, sdt, out, B, b, px, py, pz);
    c = step<7>(c,    bn, sdt, out, B, b, px, py, pz);
    c = step<10>(c,   bn, sdt, out, B, b, px, py, pz);

    c = step<2>(root, bn, sdt, out, B, b, px, py, pz);
    c = step<5>(c,    bn, sdt, out, B, b, px, py, pz);
    c = step<8>(c,    bn, sdt, out, B, b, px, py, pz);
    c = step<11>(c,   bn, sdt, out, B, b, px, py, pz);

    c = step<3>(root, bn, sdt, out, B, b, px, py, pz);
    c = step<6>(c,    bn, sdt, out, B, b, px, py, pz);
    Xf x9 = step<9>(c, bn, sdt, out, B, b, px, py, pz);

    c = step<12>(x9,  bn, sdt, out, B, b, px, py, pz);
    c = step<15>(c,   bn, sdt, out, B, b, px, py, pz);

    c = step<13>(x9,  bn, sdt, out, B, b, px, py, pz);
    c = step<16>(c,   bn, sdt, out, B, b, px, py, pz);
    c = step<18>(c,   bn, sdt, out, B, b, px, py, pz);
    c = step<20>(c,   bn, sdt, out, B, b, px, py, pz);
    c = step<22>(c,   bn, sdt, out, B, b, px, py, pz);

    c = step<14>(x9,  bn, sdt, out, B, b, px, py, pz);
    c = step<17>(c,   bn, sdt, out, B, b, px, py, pz);
    c = step<19>(c,   bn, sdt, out, B, b, px, py, pz);
    c = step<21>(c,   bn, sdt, out, B, b, px, py, pz);
    c = step<23>(c,   bn, sdt, out, B, b, px, py, pz);
}

} // namespace

extern "C" void kernel_launch(void* const* d_in, const int* in_sizes, int n_in,
                              void* d_out, int out_size, void* d_ws, size_t ws_size,
                              hipStream_t stream) {
    const float* pelvis = (const float*)d_in[0];
    const float* bones  = (const float*)d_in[1];
    const float* rest   = (const float*)d_in[2];
    const int*   idxs   = (const int*)d_in[3];
    float* out = (float*)d_out;
    int B = in_sizes[3];
    int blocks = (B + 255) / 256;
    hipLaunchKernelGGL(pose_kernel, dim3(blocks), dim3(256), 0, stream,
                       pelvis, bones, rest, idxs, out, B);
}